// Round 6
// baseline (178.707 us; speedup 1.0000x reference)
//
#include <hip/hip_runtime.h>
#include <math.h>

#define B_   16
#define N_   256
#define F_   64
#define FP_  16
#define H_   128
#define K_   14                    // Chebyshev terms
#define M_   128                   // fit nodes
#define DMAX 1.7320508075688772f   // sqrt(3): r in [0,1]^3
#define PI_F 3.14159265358979323846f
#define LROW 264                   // padded LDS row stride (f16 elems) for x / fbT

typedef _Float16 h16;
typedef __attribute__((ext_vector_type(2))) _Float16 h16x2;
typedef __attribute__((ext_vector_type(8))) _Float16 h16x8;
typedef __attribute__((ext_vector_type(4))) float    f32x4;

__device__ __forceinline__ float sp(float x) {
    // numerically stable softplus
    return fmaxf(x, 0.0f) + log1pf(expf(-fabsf(x)));
}

// ---- K1: evaluate MLP at M_ Chebyshev nodes: vals[m][f] ------------------
// grid = M_ blocks, H_ threads
__global__ void pp_vals(const float* __restrict__ mp_w1, const float* __restrict__ mp_b1,
                        const float* __restrict__ mp_w2, const float* __restrict__ mp_b2,
                        float* __restrict__ vals) {
    __shared__ float hid[H_];
    const int m = blockIdx.x, tid = threadIdx.x;
    const float th = PI_F * ((float)m + 0.5f) / (float)M_;
    const float d  = (cosf(th) + 1.0f) * 0.5f * DMAX;
    hid[tid] = sp(fmaf(d, mp_w1[tid], mp_b1[tid]));
    __syncthreads();
    if (tid < F_) {
        float z = mp_b2[tid];
        #pragma unroll 8
        for (int h = 0; h < H_; ++h)
            z = fmaf(hid[h], mp_w2[h * F_ + tid], z);
        vals[m * F_ + tid] = sp(z);
    }
}

// ---- K2: Chebyshev fit: c[k][f] from vals (Gauss-Chebyshev DCT) ----------
// grid = 1 block, 256 threads
__global__ void pp_fit(const float* __restrict__ vals, float* __restrict__ c) {
    const int tid = threadIdx.x;
    const int f = tid & 63;
    #pragma unroll
    for (int p = 0; p < 4; ++p) {
        const int k = (tid >> 6) + p * 4;
        if (k < K_) {
            float s = 0.0f;
            for (int m = 0; m < M_; ++m) {
                const float th = PI_F * ((float)m + 0.5f) / (float)M_;
                s = fmaf(vals[m * F_ + f], cosf((float)k * th), s);
            }
            c[k * F_ + f] = (k == 0) ? s / (float)M_ : 2.0f * s / (float)M_;
        }
    }
}

// ---- K3: f_bar via Chebyshev-factored f16 MFMA ---------------------------
// grid = B_*(N_/16) = 256 blocks, 256 threads (4 waves = 4 j-quarters)
__global__ __launch_bounds__(256) void pp_fbar_mfma(
        const float* __restrict__ r, const float* __restrict__ fb,
        const float* __restrict__ c, float* __restrict__ fbar_out) {
    const int tid = threadIdx.x;
    const int b   = blockIdx.x >> 4;
    const int i0  = (blockIdx.x & 15) << 4;

    __shared__ h16   s_x[16 * LROW];        // x_ij tile, f16      (8448 B)
    __shared__ h16   s_fbT[F_ * LROW];      // fb transposed, f16  (33792 B)
    __shared__ float s_c[K_ * F_];          // cheb coeffs         (3584 B)
    __shared__ float s_part[4][16 * 68];    // per-wave partials   (17408 B)
    __shared__ float s_ri[16 * 3];          // i-tile coords

    // ---- stage: i-tile coords, cheb coeffs, fb^T (f32 -> f16) ----
    if (tid < 48) s_ri[tid] = r[((size_t)b * N_ + i0) * 3 + tid];
    for (int p = 0; p < 4; ++p) {
        const int idx = p * 256 + tid;
        if (idx < K_ * F_) s_c[idx] = c[idx];
    }
    {
        const float* fbb = fb + (size_t)b * N_ * F_;
        const int f4 = tid & 15;          // float4 group in f
        const int jp = tid >> 4;          // j-pair selector
        #pragma unroll
        for (int jb = 0; jb < 8; ++jb) {
            const int j0 = jb * 32 + jp * 2;
            const float4 v0 = *(const float4*)(fbb + (size_t)j0 * F_ + f4 * 4);
            const float4 v1 = *(const float4*)(fbb + (size_t)(j0 + 1) * F_ + f4 * 4);
            const float a0[4] = {v0.x, v0.y, v0.z, v0.w};
            const float a1[4] = {v1.x, v1.y, v1.z, v1.w};
            #pragma unroll
            for (int ff = 0; ff < 4; ++ff) {
                h16x2 pk; pk.x = (h16)a0[ff]; pk.y = (h16)a1[ff];
                *(h16x2*)&s_fbT[(f4 * 4 + ff) * LROW + j0] = pk;
            }
        }
    }
    __syncthreads();

    // ---- x tile: thread j computes x for all 16 i ----
    {
        const int j = tid;
        const float xj = r[((size_t)b * N_ + j) * 3 + 0];
        const float yj = r[((size_t)b * N_ + j) * 3 + 1];
        const float zj = r[((size_t)b * N_ + j) * 3 + 2];
        const float sc = 2.0f / DMAX;
        #pragma unroll
        for (int m = 0; m < 16; ++m) {
            const float dx = s_ri[m * 3 + 0] - xj;
            const float dy = s_ri[m * 3 + 1] - yj;
            const float dz = s_ri[m * 3 + 2] - zj;
            const float sq = fmaf(dx, dx, fmaf(dy, dy, dz * dz));
            const float d  = sq > 0.0f ? sqrtf(sq) : 0.0f;
            s_x[m * LROW + j] = (h16)(fmaf(d, sc, -1.0f));
        }
    }
    __syncthreads();

    // ---- fragments: wave wv owns j in [wv*64, wv*64+64), 2 chunks of 32 ----
    const int wv   = tid >> 6;
    const int lane = tid & 63;
    const int ln   = lane & 15;          // A-row m / B-col n
    const int q    = lane >> 4;          // quad

    h16x8 bfrag[2][4];
    h16x8 x8[2];
    #pragma unroll
    for (int cc = 0; cc < 2; ++cc) {
        const int j0 = wv * 64 + cc * 32;
        x8[cc] = *(const h16x8*)&s_x[ln * LROW + j0 + q * 8];
        #pragma unroll
        for (int ft = 0; ft < 4; ++ft)
            bfrag[cc][ft] = *(const h16x8*)&s_fbT[(ft * 16 + ln) * LROW + j0 + q * 8];
    }

    h16x8 ones, twox[2], ta[2], tb[2];
    #pragma unroll
    for (int e = 0; e < 8; ++e) ones[e] = (h16)1.0f;
    #pragma unroll
    for (int cc = 0; cc < 2; ++cc) {
        twox[cc] = x8[cc] + x8[cc];
        ta[cc] = ones;       // T_0
        tb[cc] = x8[cc];     // T_1
    }

    f32x4 facc[4];
    #pragma unroll
    for (int ft = 0; ft < 4; ++ft) facc[ft] = (f32x4){0.f, 0.f, 0.f, 0.f};
    const f32x4 z4 = (f32x4){0.f, 0.f, 0.f, 0.f};

    // ---- K_ Chebyshev terms: 8 MFMAs each, fold c_k, advance recurrence ----
    for (int k = 0; k < K_; ++k) {
        f32x4 acc[4];
        #pragma unroll
        for (int ft = 0; ft < 4; ++ft) {
            acc[ft] = __builtin_amdgcn_mfma_f32_16x16x32_f16(ta[0], bfrag[0][ft], z4, 0, 0, 0);
            acc[ft] = __builtin_amdgcn_mfma_f32_16x16x32_f16(ta[1], bfrag[1][ft], acc[ft], 0, 0, 0);
        }
        #pragma unroll
        for (int ft = 0; ft < 4; ++ft) {
            const float ck = s_c[k * F_ + ft * 16 + ln];
            facc[ft].x = fmaf(ck, acc[ft].x, facc[ft].x);
            facc[ft].y = fmaf(ck, acc[ft].y, facc[ft].y);
            facc[ft].z = fmaf(ck, acc[ft].z, facc[ft].z);
            facc[ft].w = fmaf(ck, acc[ft].w, facc[ft].w);
        }
        #pragma unroll
        for (int cc = 0; cc < 2; ++cc) {
            const h16x8 tn = twox[cc] * tb[cc] - ta[cc];
            ta[cc] = tb[cc];
            tb[cc] = tn;
        }
    }

    // ---- cross-wave reduce: C layout col=ln, row=q*4+rr ----
    #pragma unroll
    for (int ft = 0; ft < 4; ++ft) {
        const float v[4] = {facc[ft].x, facc[ft].y, facc[ft].z, facc[ft].w};
        #pragma unroll
        for (int rr = 0; rr < 4; ++rr)
            s_part[wv][(q * 4 + rr) * 68 + ft * 16 + ln] = v[rr];
    }
    __syncthreads();

    {
        const int f  = tid & 63;
        const int ig = tid >> 6;
        #pragma unroll
        for (int p = 0; p < 4; ++p) {
            const int i = ig * 4 + p;
            const float s = s_part[0][i * 68 + f] + s_part[1][i * 68 + f]
                          + s_part[2][i * 68 + f] + s_part[3][i * 68 + f];
            fbar_out[((size_t)(b * N_ + i0 + i)) * F_ + f] = sp(s);
        }
    }
}

// ---- K4: pointwise MLP F -> 128 -> F' on 4096 rows -----------------------
// grid = B_*N_/2 = 2048 blocks, 256 threads (2 rows per block)
__global__ __launch_bounds__(256) void pp_mlp(
        const float* __restrict__ fbar,
        const float* __restrict__ pc_w1, const float* __restrict__ pc_b1,
        const float* __restrict__ pc_w2, const float* __restrict__ pc_b2,
        float* __restrict__ out) {
    const int tid  = threadIdx.x;
    const int row0 = blockIdx.x * 2;

    __shared__ float s_fb[2 * F_];
    __shared__ float s_h2[2 * H_];

    if (tid < 2 * F_)
        s_fb[tid] = fbar[(size_t)row0 * F_ + tid];
    __syncthreads();

    {
        const int ii = tid >> 7, h = tid & 127;
        float z = pc_b1[h];
        #pragma unroll 8
        for (int f = 0; f < F_; ++f)
            z = fmaf(s_fb[ii * F_ + f], pc_w1[f * H_ + h], z);
        s_h2[tid] = sp(z);
    }
    __syncthreads();

    if (tid < 2 * FP_) {
        const int ii = tid >> 4, p = tid & 15;
        float z = pc_b2[p];
        #pragma unroll 8
        for (int h = 0; h < H_; ++h)
            z = fmaf(s_h2[ii * H_ + h], pc_w2[h * FP_ + p], z);
        out[(size_t)(row0 + ii) * FP_ + p] = sp(z);
    }
}

extern "C" void kernel_launch(void* const* d_in, const int* in_sizes, int n_in,
                              void* d_out, int out_size, void* d_ws, size_t ws_size,
                              hipStream_t stream) {
    const float* r_batch = (const float*)d_in[0];
    const float* f_batch = (const float*)d_in[1];
    const float* mp_w1   = (const float*)d_in[2];
    const float* mp_b1   = (const float*)d_in[3];
    const float* mp_w2   = (const float*)d_in[4];
    const float* mp_b2   = (const float*)d_in[5];
    const float* pc_w1   = (const float*)d_in[6];
    const float* pc_b1   = (const float*)d_in[7];
    const float* pc_w2   = (const float*)d_in[8];
    const float* pc_b2   = (const float*)d_in[9];
    float* out = (float*)d_out;

    float* vals = (float*)d_ws;                        // 32 KB  (128 x 64)
    float* chb  = (float*)((char*)d_ws + 32768);       // 3.6 KB (14 x 64)
    float* fbar = (float*)((char*)d_ws + 65536);       // 1 MB   (4096 x 64)

    pp_vals<<<M_, H_, 0, stream>>>(mp_w1, mp_b1, mp_w2, mp_b2, vals);
    pp_fit<<<1, 256, 0, stream>>>(vals, chb);
    pp_fbar_mfma<<<B_ * (N_ / 16), 256, 0, stream>>>(r_batch, f_batch, chb, fbar);
    pp_mlp<<<B_ * N_ / 2, 256, 0, stream>>>(fbar, pc_w1, pc_b1, pc_w2, pc_b2, out);
}

// Round 7
// 100.304 us; speedup vs baseline: 1.7817x; 1.7817x over previous
//
#include <hip/hip_runtime.h>
#include <math.h>

#define B_   16
#define N_   256
#define F_   64
#define FP_  16
#define H_   128
#define K_   14                    // Chebyshev terms
#define M_   128                   // fit nodes
#define DMAX 1.7320508075688772f   // sqrt(3): r in [0,1]^3
#define PI_F 3.14159265358979323846f
#define LROW 264                   // padded LDS row stride (f16 elems) for x / fbT

typedef _Float16 h16;
typedef __attribute__((ext_vector_type(2))) _Float16 h16x2;
typedef __attribute__((ext_vector_type(8))) _Float16 h16x8;
typedef __attribute__((ext_vector_type(4))) float    f32x4;

__device__ __forceinline__ float sp(float x) {
    // numerically stable softplus
    return fmaxf(x, 0.0f) + log1pf(expf(-fabsf(x)));
}

// ---- K1: evaluate MLP at M_ Chebyshev nodes: vals[m][f] ------------------
// grid = M_ blocks, H_ threads
__global__ void pp_vals(const float* __restrict__ mp_w1, const float* __restrict__ mp_b1,
                        const float* __restrict__ mp_w2, const float* __restrict__ mp_b2,
                        float* __restrict__ vals) {
    __shared__ float hid[H_];
    const int m = blockIdx.x, tid = threadIdx.x;
    const float th = PI_F * ((float)m + 0.5f) / (float)M_;
    const float d  = (cosf(th) + 1.0f) * 0.5f * DMAX;
    hid[tid] = sp(fmaf(d, mp_w1[tid], mp_b1[tid]));
    __syncthreads();
    if (tid < F_) {
        float z = mp_b2[tid];
        #pragma unroll 8
        for (int h = 0; h < H_; ++h)
            z = fmaf(hid[h], mp_w2[h * F_ + tid], z);
        vals[m * F_ + tid] = sp(z);
    }
}

// ---- K2: Chebyshev fit c[k][f] (Gauss-Chebyshev DCT), parallel over k ----
// grid = K_ blocks, 256 threads (64 f x 4 m-groups of 32)
__global__ void pp_fit(const float* __restrict__ vals, float* __restrict__ c) {
    __shared__ float part[4][F_];
    const int k   = blockIdx.x;
    const int tid = threadIdx.x;
    const int f   = tid & 63;
    const int g   = tid >> 6;
    float s = 0.0f;
    #pragma unroll 8
    for (int mm = 0; mm < M_ / 4; ++mm) {
        const int m = g * (M_ / 4) + mm;
        const float th = PI_F * ((float)m + 0.5f) / (float)M_;
        s = fmaf(vals[m * F_ + f], __cosf((float)k * th), s);
    }
    part[g][f] = s;
    __syncthreads();
    if (tid < F_) {
        const float t = part[0][f] + part[1][f] + part[2][f] + part[3][f];
        c[k * F_ + f] = (k == 0) ? t / (float)M_ : 2.0f * t / (float)M_;
    }
}

// ---- K3: f_bar via Chebyshev-factored f16 MFMA ---------------------------
// grid = B_*(N_/16) = 256 blocks, 256 threads (4 waves = 4 j-quarters)
__global__ __launch_bounds__(256) void pp_fbar_mfma(
        const float* __restrict__ r, const float* __restrict__ fb,
        const float* __restrict__ c, float* __restrict__ fbar_out) {
    const int tid = threadIdx.x;
    const int b   = blockIdx.x >> 4;
    const int i0  = (blockIdx.x & 15) << 4;

    __shared__ h16   s_x[16 * LROW];        // x_ij tile, f16      (8448 B)
    __shared__ h16   s_fbT[F_ * LROW];      // fb transposed, f16  (33792 B)
    __shared__ float s_c[K_ * F_];          // cheb coeffs         (3584 B)
    __shared__ float s_part[4][16 * 68];    // per-wave partials   (17408 B)
    __shared__ float s_ri[16 * 3];          // i-tile coords

    // ---- stage: i-tile coords, cheb coeffs, fb^T (f32 -> f16) ----
    if (tid < 48) s_ri[tid] = r[((size_t)b * N_ + i0) * 3 + tid];
    for (int p = 0; p < 4; ++p) {
        const int idx = p * 256 + tid;
        if (idx < K_ * F_) s_c[idx] = c[idx];
    }
    {
        const float* fbb = fb + (size_t)b * N_ * F_;
        const int f4 = tid & 15;          // float4 group in f
        const int jp = tid >> 4;          // j-pair selector
        #pragma unroll
        for (int jb = 0; jb < 8; ++jb) {
            const int j0 = jb * 32 + jp * 2;
            const float4 v0 = *(const float4*)(fbb + (size_t)j0 * F_ + f4 * 4);
            const float4 v1 = *(const float4*)(fbb + (size_t)(j0 + 1) * F_ + f4 * 4);
            const float a0[4] = {v0.x, v0.y, v0.z, v0.w};
            const float a1[4] = {v1.x, v1.y, v1.z, v1.w};
            #pragma unroll
            for (int ff = 0; ff < 4; ++ff) {
                h16x2 pk; pk.x = (h16)a0[ff]; pk.y = (h16)a1[ff];
                *(h16x2*)&s_fbT[(f4 * 4 + ff) * LROW + j0] = pk;
            }
        }
    }
    __syncthreads();

    // ---- x tile: thread j computes x for all 16 i ----
    {
        const int j = tid;
        const float xj = r[((size_t)b * N_ + j) * 3 + 0];
        const float yj = r[((size_t)b * N_ + j) * 3 + 1];
        const float zj = r[((size_t)b * N_ + j) * 3 + 2];
        const float sc = 2.0f / DMAX;
        #pragma unroll
        for (int m = 0; m < 16; ++m) {
            const float dx = s_ri[m * 3 + 0] - xj;
            const float dy = s_ri[m * 3 + 1] - yj;
            const float dz = s_ri[m * 3 + 2] - zj;
            const float sq = fmaf(dx, dx, fmaf(dy, dy, dz * dz));
            const float d  = sq > 0.0f ? sqrtf(sq) : 0.0f;
            s_x[m * LROW + j] = (h16)(fmaf(d, sc, -1.0f));
        }
    }
    __syncthreads();

    // ---- fragments: wave wv owns j in [wv*64, wv*64+64), 2 chunks of 32 ----
    const int wv   = tid >> 6;
    const int lane = tid & 63;
    const int ln   = lane & 15;          // A-row m / B-col n
    const int q    = lane >> 4;          // quad

    h16x8 bfrag[2][4];
    h16x8 x8[2];
    #pragma unroll
    for (int cc = 0; cc < 2; ++cc) {
        const int j0 = wv * 64 + cc * 32;
        x8[cc] = *(const h16x8*)&s_x[ln * LROW + j0 + q * 8];
        #pragma unroll
        for (int ft = 0; ft < 4; ++ft)
            bfrag[cc][ft] = *(const h16x8*)&s_fbT[(ft * 16 + ln) * LROW + j0 + q * 8];
    }

    h16x8 ones, twox[2], ta[2], tb[2];
    #pragma unroll
    for (int e = 0; e < 8; ++e) ones[e] = (h16)1.0f;
    #pragma unroll
    for (int cc = 0; cc < 2; ++cc) {
        twox[cc] = x8[cc] + x8[cc];
        ta[cc] = ones;       // T_0
        tb[cc] = x8[cc];     // T_1
    }

    f32x4 facc[4];
    #pragma unroll
    for (int ft = 0; ft < 4; ++ft) facc[ft] = (f32x4){0.f, 0.f, 0.f, 0.f};
    const f32x4 z4 = (f32x4){0.f, 0.f, 0.f, 0.f};

    // ---- K_ Chebyshev terms: 8 MFMAs each, fold c_k, advance recurrence ----
    for (int k = 0; k < K_; ++k) {
        f32x4 acc[4];
        #pragma unroll
        for (int ft = 0; ft < 4; ++ft) {
            acc[ft] = __builtin_amdgcn_mfma_f32_16x16x32_f16(ta[0], bfrag[0][ft], z4, 0, 0, 0);
            acc[ft] = __builtin_amdgcn_mfma_f32_16x16x32_f16(ta[1], bfrag[1][ft], acc[ft], 0, 0, 0);
        }
        #pragma unroll
        for (int ft = 0; ft < 4; ++ft) {
            const float ck = s_c[k * F_ + ft * 16 + ln];
            facc[ft].x = fmaf(ck, acc[ft].x, facc[ft].x);
            facc[ft].y = fmaf(ck, acc[ft].y, facc[ft].y);
            facc[ft].z = fmaf(ck, acc[ft].z, facc[ft].z);
            facc[ft].w = fmaf(ck, acc[ft].w, facc[ft].w);
        }
        #pragma unroll
        for (int cc = 0; cc < 2; ++cc) {
            const h16x8 tn = twox[cc] * tb[cc] - ta[cc];
            ta[cc] = tb[cc];
            tb[cc] = tn;
        }
    }

    // ---- cross-wave reduce: C layout col=ln, row=q*4+rr ----
    #pragma unroll
    for (int ft = 0; ft < 4; ++ft) {
        const float v[4] = {facc[ft].x, facc[ft].y, facc[ft].z, facc[ft].w};
        #pragma unroll
        for (int rr = 0; rr < 4; ++rr)
            s_part[wv][(q * 4 + rr) * 68 + ft * 16 + ln] = v[rr];
    }
    __syncthreads();

    {
        const int f  = tid & 63;
        const int ig = tid >> 6;
        #pragma unroll
        for (int p = 0; p < 4; ++p) {
            const int i = ig * 4 + p;
            const float s = s_part[0][i * 68 + f] + s_part[1][i * 68 + f]
                          + s_part[2][i * 68 + f] + s_part[3][i * 68 + f];
            fbar_out[((size_t)(b * N_ + i0 + i)) * F_ + f] = sp(s);
        }
    }
}

// ---- K4: pointwise MLP F -> 128 -> F' on 4096 rows -----------------------
// grid = B_*N_/2 = 2048 blocks, 256 threads (2 rows per block)
__global__ __launch_bounds__(256) void pp_mlp(
        const float* __restrict__ fbar,
        const float* __restrict__ pc_w1, const float* __restrict__ pc_b1,
        const float* __restrict__ pc_w2, const float* __restrict__ pc_b2,
        float* __restrict__ out) {
    const int tid  = threadIdx.x;
    const int row0 = blockIdx.x * 2;

    __shared__ float s_fb[2 * F_];
    __shared__ float s_h2[2 * H_];

    if (tid < 2 * F_)
        s_fb[tid] = fbar[(size_t)row0 * F_ + tid];
    __syncthreads();

    {
        const int ii = tid >> 7, h = tid & 127;
        float z = pc_b1[h];
        #pragma unroll 8
        for (int f = 0; f < F_; ++f)
            z = fmaf(s_fb[ii * F_ + f], pc_w1[f * H_ + h], z);
        s_h2[tid] = sp(z);
    }
    __syncthreads();

    if (tid < 2 * FP_) {
        const int ii = tid >> 4, p = tid & 15;
        float z = pc_b2[p];
        #pragma unroll 8
        for (int h = 0; h < H_; ++h)
            z = fmaf(s_h2[ii * H_ + h], pc_w2[h * FP_ + p], z);
        out[(size_t)(row0 + ii) * FP_ + p] = sp(z);
    }
}

extern "C" void kernel_launch(void* const* d_in, const int* in_sizes, int n_in,
                              void* d_out, int out_size, void* d_ws, size_t ws_size,
                              hipStream_t stream) {
    const float* r_batch = (const float*)d_in[0];
    const float* f_batch = (const float*)d_in[1];
    const float* mp_w1   = (const float*)d_in[2];
    const float* mp_b1   = (const float*)d_in[3];
    const float* mp_w2   = (const float*)d_in[4];
    const float* mp_b2   = (const float*)d_in[5];
    const float* pc_w1   = (const float*)d_in[6];
    const float* pc_b1   = (const float*)d_in[7];
    const float* pc_w2   = (const float*)d_in[8];
    const float* pc_b2   = (const float*)d_in[9];
    float* out = (float*)d_out;

    float* vals = (float*)d_ws;                        // 32 KB  (128 x 64)
    float* chb  = (float*)((char*)d_ws + 32768);       // 3.6 KB (14 x 64)
    float* fbar = (float*)((char*)d_ws + 65536);       // 1 MB   (4096 x 64)

    pp_vals<<<M_, H_, 0, stream>>>(mp_w1, mp_b1, mp_w2, mp_b2, vals);
    pp_fit<<<K_, 256, 0, stream>>>(vals, chb);
    pp_fbar_mfma<<<B_ * (N_ / 16), 256, 0, stream>>>(r_batch, f_batch, chb, fbar);
    pp_mlp<<<B_ * N_ / 2, 256, 0, stream>>>(fbar, pc_w1, pc_b1, pc_w2, pc_b2, out);
}

// Round 8
// 99.596 us; speedup vs baseline: 1.7943x; 1.0071x over previous
//
#include <hip/hip_runtime.h>
#include <math.h>

#define B_   16
#define N_   256
#define F_   64
#define FP_  16
#define H_   128
#define K_   14                    // Chebyshev terms
#define M_   128                   // fit nodes
#define DMAX 1.7320508075688772f   // sqrt(3): r in [0,1]^3
#define PI_F 3.14159265358979323846f
#define JL   128                   // j per block (half of N)
#define LRJ  136                   // padded LDS row stride (h16) for 128-j rows

typedef _Float16 h16;
typedef __attribute__((ext_vector_type(2))) _Float16 h16x2;
typedef __attribute__((ext_vector_type(8))) _Float16 h16x8;
typedef __attribute__((ext_vector_type(4))) float    f32x4;

__device__ __forceinline__ float sp(float x) {
    // numerically stable softplus
    return fmaxf(x, 0.0f) + log1pf(expf(-fabsf(x)));
}

// ---- K1: evaluate MLP at M_ Chebyshev nodes: vals[m][f] ------------------
// grid = M_ blocks, H_ threads
__global__ void pp_vals(const float* __restrict__ mp_w1, const float* __restrict__ mp_b1,
                        const float* __restrict__ mp_w2, const float* __restrict__ mp_b2,
                        float* __restrict__ vals) {
    __shared__ float hid[H_];
    const int m = blockIdx.x, tid = threadIdx.x;
    const float th = PI_F * ((float)m + 0.5f) / (float)M_;
    const float d  = (cosf(th) + 1.0f) * 0.5f * DMAX;
    hid[tid] = sp(fmaf(d, mp_w1[tid], mp_b1[tid]));
    __syncthreads();
    if (tid < F_) {
        float z = mp_b2[tid];
        #pragma unroll 8
        for (int h = 0; h < H_; ++h)
            z = fmaf(hid[h], mp_w2[h * F_ + tid], z);
        vals[m * F_ + tid] = sp(z);
    }
}

// ---- K2: Chebyshev fit c[k][f] (Gauss-Chebyshev DCT), parallel over k ----
// grid = K_ blocks, 256 threads (64 f x 4 m-groups of 32)
__global__ void pp_fit(const float* __restrict__ vals, float* __restrict__ c) {
    __shared__ float part[4][F_];
    const int k   = blockIdx.x;
    const int tid = threadIdx.x;
    const int f   = tid & 63;
    const int g   = tid >> 6;
    float s = 0.0f;
    #pragma unroll 8
    for (int mm = 0; mm < M_ / 4; ++mm) {
        const int m = g * (M_ / 4) + mm;
        const float th = PI_F * ((float)m + 0.5f) / (float)M_;
        s = fmaf(vals[m * F_ + f], __cosf((float)k * th), s);
    }
    part[g][f] = s;
    __syncthreads();
    if (tid < F_) {
        const float t = part[0][f] + part[1][f] + part[2][f] + part[3][f];
        c[k * F_ + f] = (k == 0) ? t / (float)M_ : 2.0f * t / (float)M_;
    }
}

// ---- K3: partial f_bar via Chebyshev-factored f16 MFMA, j-split x2 -------
// grid = B_*(N_/16)*2 = 512 blocks, 256 threads (4 waves x 32-j windows)
__global__ __launch_bounds__(256) void pp_fbar_mfma(
        const float* __restrict__ r, const float* __restrict__ fb,
        const float* __restrict__ c, float* __restrict__ part_out) {
    const int tid = threadIdx.x;
    const int b   = blockIdx.x >> 5;
    const int w   = blockIdx.x & 31;
    const int i0  = (w >> 1) << 4;       // 16-row i-tile
    const int jh  = w & 1;               // j half: [jh*128, jh*128+128)

    __shared__ h16   s_x[16 * LRJ];                  // x tile        (4352 B)
    __shared__ __align__(16) char s_mem[F_ * LRJ * 2];  // fbT -> part (17408 B)
    __shared__ float s_c[K_ * F_];                   //               (3584 B)
    __shared__ float s_ri[16 * 3];
    h16*   s_fbT  = (h16*)s_mem;          // [64][LRJ] f16, dead after frag loads
    float* s_part = (float*)s_mem;        // [4][16][68] per-wave C partials

    // ---- phase A: i-tile coords, cheb coeffs, fb^T (f32 -> f16, 128 j) ----
    if (tid < 48) s_ri[tid] = r[((size_t)b * N_ + i0) * 3 + tid];
    #pragma unroll
    for (int p = 0; p < 4; ++p) {
        const int idx = p * 256 + tid;
        if (idx < K_ * F_) s_c[idx] = c[idx];
    }
    {
        const float* fbb = fb + ((size_t)b * N_ + jh * JL) * F_;
        const int f4 = tid & 15;          // float4 group in f
        const int jp = tid >> 4;          // j-pair selector
        #pragma unroll
        for (int jb = 0; jb < 4; ++jb) {
            const int j0 = jb * 32 + jp * 2;   // local j
            const float4 v0 = *(const float4*)(fbb + (size_t)j0 * F_ + f4 * 4);
            const float4 v1 = *(const float4*)(fbb + (size_t)(j0 + 1) * F_ + f4 * 4);
            const float a0[4] = {v0.x, v0.y, v0.z, v0.w};
            const float a1[4] = {v1.x, v1.y, v1.z, v1.w};
            #pragma unroll
            for (int ff = 0; ff < 4; ++ff) {
                h16x2 pk; pk.x = (h16)a0[ff]; pk.y = (h16)a1[ff];
                *(h16x2*)&s_fbT[(f4 * 4 + ff) * LRJ + j0] = pk;
            }
        }
    }
    __syncthreads();

    // ---- phase B: x tile: thread (lj, half) computes 8 i's ----
    {
        const int lj   = tid & 127;
        const int half = tid >> 7;
        const int gj   = jh * JL + lj;
        const float xj = r[((size_t)b * N_ + gj) * 3 + 0];
        const float yj = r[((size_t)b * N_ + gj) * 3 + 1];
        const float zj = r[((size_t)b * N_ + gj) * 3 + 2];
        const float sc = 2.0f / DMAX;
        #pragma unroll
        for (int mm = 0; mm < 8; ++mm) {
            const int m = half * 8 + mm;
            const float dx = s_ri[m * 3 + 0] - xj;
            const float dy = s_ri[m * 3 + 1] - yj;
            const float dz = s_ri[m * 3 + 2] - zj;
            const float sq = fmaf(dx, dx, fmaf(dy, dy, dz * dz));
            const float d  = sq > 0.0f ? sqrtf(sq) : 0.0f;
            s_x[m * LRJ + lj] = (h16)(fmaf(d, sc, -1.0f));
        }
    }
    __syncthreads();

    // ---- phase C: fragments; wave wv owns local j [wv*32, wv*32+32) ----
    const int wv   = tid >> 6;
    const int lane = tid & 63;
    const int ln   = lane & 15;          // A-row m / B-col n
    const int q    = lane >> 4;          // quad
    const int jo   = wv * 32 + q * 8;

    const h16x8 x8 = *(const h16x8*)&s_x[ln * LRJ + jo];
    h16x8 bfrag[4];
    #pragma unroll
    for (int ft = 0; ft < 4; ++ft)
        bfrag[ft] = *(const h16x8*)&s_fbT[(ft * 16 + ln) * LRJ + jo];
    __syncthreads();   // all fbT reads done; s_mem becomes s_part

    h16x8 ones, twox, ta, tb;
    #pragma unroll
    for (int e = 0; e < 8; ++e) ones[e] = (h16)1.0f;
    twox = x8 + x8;
    ta = ones;       // T_0
    tb = x8;         // T_1

    f32x4 facc[4];
    #pragma unroll
    for (int ft = 0; ft < 4; ++ft) facc[ft] = (f32x4){0.f, 0.f, 0.f, 0.f};
    const f32x4 z4 = (f32x4){0.f, 0.f, 0.f, 0.f};

    // ---- phase D: K_ terms: 4 MFMAs each, fold c_k, advance recurrence ----
    for (int k = 0; k < K_; ++k) {
        #pragma unroll
        for (int ft = 0; ft < 4; ++ft) {
            const f32x4 acc = __builtin_amdgcn_mfma_f32_16x16x32_f16(ta, bfrag[ft], z4, 0, 0, 0);
            const float ck = s_c[k * F_ + ft * 16 + ln];
            facc[ft].x = fmaf(ck, acc.x, facc[ft].x);
            facc[ft].y = fmaf(ck, acc.y, facc[ft].y);
            facc[ft].z = fmaf(ck, acc.z, facc[ft].z);
            facc[ft].w = fmaf(ck, acc.w, facc[ft].w);
        }
        const h16x8 tn = twox * tb - ta;
        ta = tb;
        tb = tn;
    }

    // ---- cross-wave partial write: C layout col=ln, row=q*4+rr ----
    #pragma unroll
    for (int ft = 0; ft < 4; ++ft) {
        const float v[4] = {facc[ft].x, facc[ft].y, facc[ft].z, facc[ft].w};
        #pragma unroll
        for (int rr = 0; rr < 4; ++rr)
            s_part[(wv * 16 + q * 4 + rr) * 68 + ft * 16 + ln] = v[rr];
    }
    __syncthreads();

    // ---- phase E: reduce 4 waves, write partial (no softplus) ----
    {
        const int f  = tid & 63;
        const int ig = tid >> 6;
        #pragma unroll
        for (int p = 0; p < 4; ++p) {
            const int i = ig * 4 + p;
            const float s = s_part[(0 * 16 + i) * 68 + f] + s_part[(1 * 16 + i) * 68 + f]
                          + s_part[(2 * 16 + i) * 68 + f] + s_part[(3 * 16 + i) * 68 + f];
            part_out[(size_t)jh * (B_ * N_ * F_) + ((size_t)(b * N_ + i0 + i)) * F_ + f] = s;
        }
    }
}

// ---- K4: sum j-halves + softplus + pointwise MLP F -> 128 -> F' ----------
// grid = B_*N_/2 = 2048 blocks, 256 threads (2 rows per block)
__global__ __launch_bounds__(256) void pp_mlp(
        const float* __restrict__ part,
        const float* __restrict__ pc_w1, const float* __restrict__ pc_b1,
        const float* __restrict__ pc_w2, const float* __restrict__ pc_b2,
        float* __restrict__ out) {
    const int tid  = threadIdx.x;
    const int row0 = blockIdx.x * 2;

    __shared__ float s_fb[2 * F_];
    __shared__ float s_h2[2 * H_];

    if (tid < 2 * F_) {
        const size_t idx = (size_t)row0 * F_ + tid;
        s_fb[tid] = sp(part[idx] + part[(size_t)B_ * N_ * F_ + idx]);
    }
    __syncthreads();

    {
        const int ii = tid >> 7, h = tid & 127;
        float z = pc_b1[h];
        #pragma unroll 8
        for (int f = 0; f < F_; ++f)
            z = fmaf(s_fb[ii * F_ + f], pc_w1[f * H_ + h], z);
        s_h2[tid] = sp(z);
    }
    __syncthreads();

    if (tid < 2 * FP_) {
        const int ii = tid >> 4, p = tid & 15;
        float z = pc_b2[p];
        #pragma unroll 8
        for (int h = 0; h < H_; ++h)
            z = fmaf(s_h2[ii * H_ + h], pc_w2[h * FP_ + p], z);
        out[(size_t)(row0 + ii) * FP_ + p] = sp(z);
    }
}

extern "C" void kernel_launch(void* const* d_in, const int* in_sizes, int n_in,
                              void* d_out, int out_size, void* d_ws, size_t ws_size,
                              hipStream_t stream) {
    const float* r_batch = (const float*)d_in[0];
    const float* f_batch = (const float*)d_in[1];
    const float* mp_w1   = (const float*)d_in[2];
    const float* mp_b1   = (const float*)d_in[3];
    const float* mp_w2   = (const float*)d_in[4];
    const float* mp_b2   = (const float*)d_in[5];
    const float* pc_w1   = (const float*)d_in[6];
    const float* pc_b1   = (const float*)d_in[7];
    const float* pc_w2   = (const float*)d_in[8];
    const float* pc_b2   = (const float*)d_in[9];
    float* out = (float*)d_out;

    float* vals = (float*)d_ws;                        // 32 KB  (128 x 64)
    float* chb  = (float*)((char*)d_ws + 32768);       // 3.6 KB (14 x 64)
    float* part = (float*)((char*)d_ws + 65536);       // 2 MB   (2 x 4096 x 64)

    pp_vals<<<M_, H_, 0, stream>>>(mp_w1, mp_b1, mp_w2, mp_b2, vals);
    pp_fit<<<K_, 256, 0, stream>>>(vals, chb);
    pp_fbar_mfma<<<B_ * (N_ / 16) * 2, 256, 0, stream>>>(r_batch, f_batch, chb, part);
    pp_mlp<<<B_ * N_ / 2, 256, 0, stream>>>(part, pc_w1, pc_b1, pc_w2, pc_b2, out);
}